// Round 7
// baseline (132.804 us; speedup 1.0000x reference)
//
#include <hip/hip_runtime.h>
#include <stdint.h>

#define B 256
#define DIM 512
#define TOPK 4096
#define MARGIN 0.2f
#define SC_AGENT __HIP_MEMORY_SCOPE_AGENT
#define NBLK 32
#define RPB 8               /* q-rows per block */
#define NT 1024             /* threads per block */
#define PMAX 128
#define BUFCAP 60000u
#define FIX_SCALE 4294967296.0   /* 2^32; fixv exact for f32 inputs */

// ---------------- ws layout (zeroed region per call) ----------------
// ghA   u32[2048] @ 0       gSumA u64[2048] @ 8192
// gFlags u32[32]  @ 24576   gCnt u32 @ 24704   cnt1 u32 @ 24708
// buf   u32[BUFCAP] @ 24712 (not zeroed)
#define WS_ZERO_BYTES 24712

__device__ __forceinline__ uint32_t ld_rlx32(const uint32_t* p) {
    return __hip_atomic_load(p, __ATOMIC_RELAXED, SC_AGENT);
}
__device__ __forceinline__ uint64_t ld_rlx64(const uint64_t* p) {
    return __hip_atomic_load(p, __ATOMIC_RELAXED, SC_AGENT);
}
__device__ __forceinline__ void st_rlx32(uint32_t* p, uint32_t v) {
    __hip_atomic_store(p, v, __ATOMIC_RELAXED, SC_AGENT);
}
__device__ __forceinline__ uint64_t fixv(float v) {
    return (uint64_t)((double)v * FIX_SCALE + 0.5);
}

// Radix-select step over NT*PER buckets, descending. Thread tid owns chunk
// (NT-1-tid); inclusive shuffle-scan over tid == suffix sums over buckets.
// Exactly one thread writes res[0]=bucket, res[1]=remaining needed.
template <int PER, bool GLOBAL>
__device__ void selstep(const uint32_t* h, uint32_t needed,
                        uint32_t* wtot, uint32_t* res, int tid) {
    const int chunk = (NT - 1) - tid;
    uint32_t vals[PER];
    uint32_t v = 0;
#pragma unroll
    for (int k = 0; k < PER; ++k) {
        vals[k] = GLOBAL ? ld_rlx32(&h[chunk * PER + k]) : h[chunk * PER + k];
        v += vals[k];
    }
    uint32_t s = v;
    const int lane = tid & 63, wv = tid >> 6;
#pragma unroll
    for (int d = 1; d < 64; d <<= 1) {
        uint32_t t = __shfl_up(s, d, 64);
        if (lane >= d) s += t;
    }
    if (lane == 63) wtot[wv] = s;
    __syncthreads();
    uint32_t off = 0;
    for (int w = 0; w < wv; ++w) off += wtot[w];
    s += off;                       // count in buckets >= chunk*PER
    const uint32_t excl = s - v;    // count strictly above own chunk
    if (excl < needed && needed <= s) {
        uint32_t cum = excl;
#pragma unroll
        for (int k = PER - 1; k >= 0; --k) {
            const uint32_t hv = vals[k];
            if (cum + hv >= needed) {
                res[0] = (uint32_t)(chunk * PER + k);
                res[1] = needed - cum;
                break;
            }
            cum += hv;
        }
    }
    __syncthreads();
}

__global__ void __launch_bounds__(NT, 1)
triplet_kernel(const float* __restrict__ x, const int* __restrict__ lab,
               uint32_t* __restrict__ gws, float* __restrict__ out) {
    uint32_t* ghA    = gws;
    uint64_t* gSumA  = (uint64_t*)(gws + 2048);
    uint32_t* gFlags = gws + 6144;
    uint32_t* gCnt   = gws + 6176;
    uint32_t* cnt1   = gws + 6177;
    uint32_t* buf    = gws + 6178;

    __shared__ float    xi[RPB * DIM];            // 16 KB: this block's q-rows
    __shared__ float    sD[RPB][B];               // 8 KB
    __shared__ float    pbase[RPB][PMAX];         // 4 KB
    __shared__ int      pcnt[RPB];
    __shared__ int      sL[B];
    __shared__ uint32_t sh[2048];                 // count hist
    __shared__ unsigned long long ssum[2048];     // fixed-point sum hist
    __shared__ uint32_t wtot[16];
    __shared__ uint32_t res[2];
    __shared__ unsigned long long usum[16];
    __shared__ unsigned long long sAcc1, sAcc2;
    __shared__ uint32_t sBase;
    __shared__ int      sFin;

    const int bid = blockIdx.x, tid = threadIdx.x;
    const int lane = tid & 63, wv = tid >> 6;
    const int q0 = bid * RPB;
    const int n = tid & 255;
    const int rsub = tid >> 8;                    // 0..3

    // ---- stage labels, q-rows (contiguous 16 KB), zero LDS hists ----
    if (tid < B) sL[tid] = lab[tid];
    for (int i = tid; i < RPB * DIM; i += NT) xi[i] = x[q0 * DIM + i];
    for (int i = tid; i < 2048; i += NT) { sh[i] = 0; ssum[i] = 0ull; }
    if (tid < RPB) pcnt[tid] = 0;
    __syncthreads();

    // ---- D rows: thread (n, rsub) computes D[q0+rsub][n], D[q0+rsub+4][n] ----
    {
        const float4* xj4 = (const float4*)(x + n * DIM);
        const float4* xa4 = (const float4*)(xi + rsub * DIM);
        const float4* xb4 = (const float4*)(xi + (rsub + 4) * DIM);
        float acc0 = 0.f, acc1 = 0.f;
#pragma unroll 4
        for (int k4 = 0; k4 < DIM / 4; ++k4) {
            const float4 bv = xj4[k4];
            const float4 a  = xa4[k4];
            const float4 c  = xb4[k4];
            float d;
            d = a.x - bv.x; acc0 += d * d;
            d = a.y - bv.y; acc0 += d * d;
            d = a.z - bv.z; acc0 += d * d;
            d = a.w - bv.w; acc0 += d * d;
            d = c.x - bv.x; acc1 += d * d;
            d = c.y - bv.y; acc1 += d * d;
            d = c.z - bv.z; acc1 += d * d;
            d = c.w - bv.w; acc1 += d * d;
        }
        sD[rsub][n] = acc0;
        sD[rsub + 4][n] = acc1;
    }
    __syncthreads();

    // ---- compact valid positives per row (order-free: downstream commutes) ----
    if (tid < B) {
        const int p = tid;
        for (int r = 0; r < RPB; ++r) {
            const int qr = q0 + r;
            if (p < qr && sL[p] == sL[qr]) {
                const int pos = atomicAdd(&pcnt[r], 1);
                if (pos < PMAX) pbase[r][pos] = sD[r][p] + MARGIN;
            }
        }
    }
    __syncthreads();

    // ---- phase 1: count + fixed-point-sum hists over bits[31:21] ----
    for (int rg = 0; rg < 2; ++rg) {
        const int r  = rsub + rg * 4;
        const int qr = q0 + r;
        if (sL[n] == sL[qr]) continue;            // n invalid for this row
        const float dqn = sD[r][n];
        const int pc = min(pcnt[r], PMAX);
        for (int ip = 0; ip < pc; ++ip) {
            const float v = fmaxf(pbase[r][ip] - dqn, 0.0f);
            const uint32_t bk = __float_as_uint(v) >> 21;
            atomicAdd(&sh[bk], 1u);
            atomicAdd(&ssum[bk], (unsigned long long)fixv(v));
        }
    }
    __syncthreads();
    for (int i = tid; i < 2048; i += NT) {
        const uint32_t c = sh[i];
        if (c) {
            atomicAdd(&ghA[i], c);
            atomicAdd((unsigned long long*)&gSumA[i], ssum[i]);
        }
    }
    __syncthreads();   // all waves' global atomics issued before flag
    if (tid == 0) __hip_atomic_store(&gFlags[bid], 1u, __ATOMIC_RELEASE, SC_AGENT);

    // ---- single grid barrier: poll 32 flags ----
    for (;;) {
        const uint32_t f = (tid < NBLK) ? ld_rlx32(&gFlags[tid]) : 1u;
        if (__syncthreads_count(f != 0) == NT) break;
        __builtin_amdgcn_s_sleep(2);
    }
    asm volatile("" ::: "memory");

    // ---- redundant select of s0 (every block; no publish round-trip) ----
    selstep<2, true>(ghA, (uint32_t)TOPK, wtot, res, tid);
    const uint32_t s0      = res[0];
    const uint32_t needed0 = res[1];

    // ---- phase 2: append in-bucket values (1 gCnt RMW per block) ----
    uint32_t cin = 0;
    const bool haveIn = (sh[s0] != 0);            // block-local count hist
    if (haveIn) {
        for (int rg = 0; rg < 2; ++rg) {
            const int r  = rsub + rg * 4;
            const int qr = q0 + r;
            if (sL[n] == sL[qr]) continue;
            const float dqn = sD[r][n];
            const int pc = min(pcnt[r], PMAX);
            for (int ip = 0; ip < pc; ++ip) {
                const uint32_t bits = __float_as_uint(fmaxf(pbase[r][ip] - dqn, 0.0f));
                if ((bits >> 21) == s0) ++cin;
            }
        }
    }
    {
        uint32_t inc = cin;
#pragma unroll
        for (int d = 1; d < 64; d <<= 1) {
            uint32_t t2 = __shfl_up(inc, d, 64);
            if (lane >= d) inc += t2;
        }
        if (lane == 63) wtot[wv] = inc;
        __syncthreads();
        uint32_t woff = 0;
        for (int w = 0; w < wv; ++w) woff += wtot[w];
        const uint32_t myoff = woff + inc - cin;
        if (tid == 0) {
            uint32_t tot = 0;
            for (int w = 0; w < 16; ++w) tot += wtot[w];
            sBase = tot ? atomicAdd(gCnt, tot) : 0u;
        }
        __syncthreads();
        if (cin) {
            uint32_t o = sBase + myoff;
            for (int rg = 0; rg < 2; ++rg) {
                const int r  = rsub + rg * 4;
                const int qr = q0 + r;
                if (sL[n] == sL[qr]) continue;
                const float dqn = sD[r][n];
                const int pc = min(pcnt[r], PMAX);
                for (int ip = 0; ip < pc; ++ip) {
                    const uint32_t bits = __float_as_uint(fmaxf(pbase[r][ip] - dqn, 0.0f));
                    if ((bits >> 21) == s0) {
                        if (o < BUFCAP) st_rlx32(&buf[o], bits);
                        ++o;
                    }
                }
            }
        }
    }
    __syncthreads();
    if (tid == 0) {
        const uint32_t old = __hip_atomic_fetch_add(cnt1, 1u, __ATOMIC_ACQ_REL, SC_AGENT);
        sFin = (old == NBLK - 1) ? 1 : 0;
    }
    __syncthreads();
    if (!sFin) return;   // 31 blocks exit; no spinning

    // ================= finalizer (last arriver) =================
    // exact sum of all values strictly above bucket s0 (from sum-histogram)
    {
        uint64_t sb = 0;
#pragma unroll
        for (int k = 0; k < 2; ++k) {
            const uint32_t b = (uint32_t)tid * 2u + (uint32_t)k;
            if (b > s0) sb += ld_rlx64(&gSumA[b]);
        }
#pragma unroll
        for (int off = 32; off > 0; off >>= 1)
            sb += __shfl_down((unsigned long long)sb, off, 64);
        if (lane == 0) usum[wv] = sb;
        __syncthreads();
        if (tid == 0) {
            unsigned long long t = 0;
            for (int w = 0; w < 16; ++w) t += usum[w];
            sAcc1 = t;
        }
    }
    __syncthreads();

    const uint32_t nbuf = min(ld_rlx32(gCnt), BUFCAP);

    // level 2: bits[20:10] count+sum hists from buf
    for (int i = tid; i < 2048; i += NT) { sh[i] = 0; ssum[i] = 0ull; }
    __syncthreads();
    for (uint32_t i = (uint32_t)tid; i < nbuf; i += NT) {
        const uint32_t b = ld_rlx32(&buf[i]);
        const uint32_t b2 = (b >> 10) & 0x7FFu;
        atomicAdd(&sh[b2], 1u);
        atomicAdd(&ssum[b2], (unsigned long long)fixv(__uint_as_float(b)));
    }
    __syncthreads();
    selstep<2, false>(sh, needed0, wtot, res, tid);
    const uint32_t s1      = res[0];
    const uint32_t needed1 = res[1];
    {
        uint64_t sb = 0;
#pragma unroll
        for (int k = 0; k < 2; ++k) {
            const uint32_t b = (uint32_t)tid * 2u + (uint32_t)k;
            if (b > s1) sb += ssum[b];
        }
#pragma unroll
        for (int off = 32; off > 0; off >>= 1)
            sb += __shfl_down((unsigned long long)sb, off, 64);
        if (lane == 0) usum[wv] = sb;
        __syncthreads();
        if (tid == 0) {
            unsigned long long t = 0;
            for (int w = 0; w < 16; ++w) t += usum[w];
            sAcc2 = t;
        }
    }
    __syncthreads();

    // level 3: bits[9:0] within (s0,s1)
    for (int i = tid; i < 1024; i += NT) { sh[i] = 0; ssum[i] = 0ull; }
    __syncthreads();
    for (uint32_t i = (uint32_t)tid; i < nbuf; i += NT) {
        const uint32_t b = ld_rlx32(&buf[i]);
        if (((b >> 10) & 0x7FFu) == s1) {
            const uint32_t b3 = b & 0x3FFu;
            atomicAdd(&sh[b3], 1u);
            atomicAdd(&ssum[b3], (unsigned long long)fixv(__uint_as_float(b)));
        }
    }
    __syncthreads();
    selstep<1, false>(sh, needed1, wtot, res, tid);
    const uint32_t s2      = res[0];
    const uint32_t needed2 = res[1];
    const uint32_t T = (s0 << 21) | (s1 << 10) | s2;
    {
        uint64_t sb = (tid > (int)s2 && tid < 1024) ? ssum[tid] : 0ull;
#pragma unroll
        for (int off = 32; off > 0; off >>= 1)
            sb += __shfl_down((unsigned long long)sb, off, 64);
        if (lane == 0) usum[wv] = sb;
        __syncthreads();
        if (tid == 0) {
            unsigned long long t = 0;
            for (int w = 0; w < 16; ++w) t += usum[w];
            const uint64_t total = t + sAcc1 + sAcc2;
            const double tval = (double)__uint_as_float(T);
            const double loss = ((double)total * (1.0 / FIX_SCALE) +
                                 (double)needed2 * tval) / (double)TOPK;
            out[0] = (float)loss;
        }
    }
}

extern "C" void kernel_launch(void* const* d_in, const int* in_sizes, int n_in,
                              void* d_out, int out_size, void* d_ws, size_t ws_size,
                              hipStream_t stream) {
    const float* x   = (const float*)d_in[0];
    const int*   lab = (const int*)d_in[1];
    float*       out = (float*)d_out;
    uint32_t*    gws = (uint32_t*)d_ws;

    hipMemsetAsync(gws, 0, WS_ZERO_BYTES, stream);

    void* args[] = {(void*)&x, (void*)&lab, (void*)&gws, (void*)&out};
    hipLaunchCooperativeKernel((const void*)triplet_kernel, dim3(NBLK), dim3(NT),
                               args, 0, stream);
}

// Round 8
// 111.221 us; speedup vs baseline: 1.1941x; 1.1941x over previous
//
#include <hip/hip_runtime.h>
#include <stdint.h>

#define B 256
#define DIM 512
#define TOPK 4096
#define MARGIN 0.2f
#define SC_AGENT __HIP_MEMORY_SCOPE_AGENT
#define NBLK 32
#define RPB 8               /* q-rows per block */
#define NT 1024             /* threads per block */
#define PMAX 64
#define BUFCAP 60000u
#define FIX_SCALE 4294967296.0   /* 2^32 */

// ---------------- ws layout (zeroed region per call) ----------------
// ghA u32[2048] @ 0   gFlags u32[32] @ 8192   gCnt @ 8320   cnt1 @ 8324
// gSum u64 @ 8328     buf u32[BUFCAP] @ 8336 (not zeroed)
#define WS_ZERO_BYTES 8336

__device__ __forceinline__ uint32_t ld_rlx32(const uint32_t* p) {
    return __hip_atomic_load(p, __ATOMIC_RELAXED, SC_AGENT);
}
__device__ __forceinline__ uint64_t ld_rlx64(const uint64_t* p) {
    return __hip_atomic_load(p, __ATOMIC_RELAXED, SC_AGENT);
}
__device__ __forceinline__ void st_rlx32(uint32_t* p, uint32_t v) {
    __hip_atomic_store(p, v, __ATOMIC_RELAXED, SC_AGENT);
}
__device__ __forceinline__ uint64_t fixv(float v) {
    return (uint64_t)((double)v * FIX_SCALE + 0.5);
}

// Radix-select step over NT*PER buckets, descending. Thread tid owns chunk
// (NT-1-tid); inclusive shuffle-scan over tid == suffix sums over buckets.
// Exactly one thread writes res[0]=bucket, res[1]=remaining needed.
template <int PER, bool GLOBAL>
__device__ void selstep(const uint32_t* h, uint32_t needed,
                        uint32_t* wtot, uint32_t* res, int tid) {
    const int chunk = (NT - 1) - tid;
    uint32_t vals[PER];
    uint32_t v = 0;
#pragma unroll
    for (int k = 0; k < PER; ++k) {
        vals[k] = GLOBAL ? ld_rlx32(&h[chunk * PER + k]) : h[chunk * PER + k];
        v += vals[k];
    }
    uint32_t s = v;
    const int lane = tid & 63, wv = tid >> 6;
#pragma unroll
    for (int d = 1; d < 64; d <<= 1) {
        uint32_t t = __shfl_up(s, d, 64);
        if (lane >= d) s += t;
    }
    if (lane == 63) wtot[wv] = s;
    __syncthreads();
    uint32_t off = 0;
    for (int w = 0; w < wv; ++w) off += wtot[w];
    s += off;                       // count in buckets >= chunk*PER
    const uint32_t excl = s - v;    // count strictly above own chunk
    if (excl < needed && needed <= s) {
        uint32_t cum = excl;
#pragma unroll
        for (int k = PER - 1; k >= 0; --k) {
            const uint32_t hv = vals[k];
            if (cum + hv >= needed) {
                res[0] = (uint32_t)(chunk * PER + k);
                res[1] = needed - cum;
                break;
            }
            cum += hv;
        }
    }
    __syncthreads();
}

__global__ void __launch_bounds__(NT, 1)
triplet_kernel(const float* __restrict__ x, const int* __restrict__ lab,
               uint32_t* __restrict__ gws, float* __restrict__ out) {
    uint32_t* ghA    = gws;
    uint32_t* gFlags = gws + 2048;
    uint32_t* gCnt   = gws + 2080;
    uint32_t* cnt1   = gws + 2081;
    uint64_t* gSum   = (uint64_t*)(gws + 2082);   // byte 8328, 8-aligned
    uint32_t* buf    = gws + 2084;                // byte 8336

    __shared__ float    xi[RPB * DIM];            // 16 KB
    __shared__ float    sD[RPB][B];               // 8 KB
    __shared__ float    pbase[RPB][PMAX];         // 2 KB
    __shared__ int      pcnt[RPB];
    __shared__ int      sL[B];
    __shared__ uint32_t sh[4][2048];              // 32 KB privatized count hists
    __shared__ unsigned long long ssum[2048];     // 16 KB (finalizer sums)
    __shared__ uint32_t wtot[16];
    __shared__ uint32_t res[2];
    __shared__ unsigned long long usum[16];
    __shared__ unsigned long long sAcc2;
    __shared__ uint32_t sBase;
    __shared__ int      sFin;

    const int bid = blockIdx.x, tid = threadIdx.x;
    const int lane = tid & 63, wv = tid >> 6;
    const int copy = wv & 3;
    const int q0 = bid * RPB;
    const int n = tid & 255;
    const int rsub = tid >> 8;                    // 0..3

    // ---- stage labels, q-rows, zero LDS hists ----
    if (tid < B) sL[tid] = lab[tid];
    for (int i = tid; i < RPB * DIM; i += NT) xi[i] = x[q0 * DIM + i];
    for (int i = tid; i < 4 * 2048; i += NT) ((uint32_t*)sh)[i] = 0;
    if (tid < RPB) pcnt[tid] = 0;
    __syncthreads();

    // ---- D rows: thread (n, rsub) computes D[q0+rsub][n], D[q0+rsub+4][n] ----
    {
        const float4* xj4 = (const float4*)(x + n * DIM);
        const float4* xa4 = (const float4*)(xi + rsub * DIM);
        const float4* xb4 = (const float4*)(xi + (rsub + 4) * DIM);
        float acc0 = 0.f, acc1 = 0.f;
#pragma unroll 4
        for (int k4 = 0; k4 < DIM / 4; ++k4) {
            const float4 bv = xj4[k4];
            const float4 a  = xa4[k4];
            const float4 c  = xb4[k4];
            float d;
            d = a.x - bv.x; acc0 += d * d;
            d = a.y - bv.y; acc0 += d * d;
            d = a.z - bv.z; acc0 += d * d;
            d = a.w - bv.w; acc0 += d * d;
            d = c.x - bv.x; acc1 += d * d;
            d = c.y - bv.y; acc1 += d * d;
            d = c.z - bv.z; acc1 += d * d;
            d = c.w - bv.w; acc1 += d * d;
        }
        sD[rsub][n] = acc0;
        sD[rsub + 4][n] = acc1;
    }
    __syncthreads();

    // ---- compact valid positives per row (order-free: downstream commutes) ----
    if (tid < B) {
        const int p = tid;
        for (int r = 0; r < RPB; ++r) {
            const int qr = q0 + r;
            if (p < qr && sL[p] == sL[qr]) {
                const int pos = atomicAdd(&pcnt[r], 1);
                if (pos < PMAX) pbase[r][pos] = sD[r][p] + MARGIN;
            }
        }
    }
    __syncthreads();

    // ---- phase 1: count hist over bits[31:21]; zeros counted in registers ----
    {
        uint32_t zc = 0;
        for (int rg = 0; rg < 2; ++rg) {
            const int r  = rsub + rg * 4;
            const int qr = q0 + r;
            if (sL[n] == sL[qr]) continue;        // n invalid for this row
            const float dqn = sD[r][n];
            const int pc = min(pcnt[r], PMAX);
            for (int ip = 0; ip < pc; ++ip) {
                const float v = fmaxf(pbase[r][ip] - dqn, 0.0f);
                if (v == 0.0f) { ++zc; continue; }  // bucket 0; no atomic
                atomicAdd(&sh[copy][__float_as_uint(v) >> 21], 1u);
            }
        }
#pragma unroll
        for (int off = 32; off > 0; off >>= 1) zc += __shfl_down(zc, off, 64);
        if (lane == 0 && zc) atomicAdd(&sh[copy][0], zc);
    }
    __syncthreads();
    for (int i = tid; i < 2048; i += NT) {
        const uint32_t c = sh[0][i] + sh[1][i] + sh[2][i] + sh[3][i];
        if (c) atomicAdd(&ghA[i], c);
    }
    __syncthreads();   // all waves' global atomics issued before flag
    if (tid == 0) __hip_atomic_store(&gFlags[bid], 1u, __ATOMIC_RELEASE, SC_AGENT);

    // ---- single grid barrier: poll 32 flags ----
    for (;;) {
        const uint32_t f = (tid < NBLK) ? ld_rlx32(&gFlags[tid]) : 1u;
        if (__syncthreads_count(f != 0) == NT) break;
        __builtin_amdgcn_s_sleep(2);
    }
    asm volatile("" ::: "memory");

    // ---- redundant select of s0 (every block; no publish round-trip) ----
    selstep<2, true>(ghA, (uint32_t)TOPK, wtot, res, tid);
    const uint32_t s0      = res[0];
    const uint32_t needed0 = res[1];

    // ---- phase 2: register sum above s0 + append in-bucket values ----
    uint64_t sumA = 0;
    uint32_t cin  = 0;
    for (int rg = 0; rg < 2; ++rg) {
        const int r  = rsub + rg * 4;
        const int qr = q0 + r;
        if (sL[n] == sL[qr]) continue;
        const float dqn = sD[r][n];
        const int pc = min(pcnt[r], PMAX);
        for (int ip = 0; ip < pc; ++ip) {
            const float v = fmaxf(pbase[r][ip] - dqn, 0.0f);
            const uint32_t bk = __float_as_uint(v) >> 21;
            if (bk > s0) sumA += fixv(v);
            else if (bk == s0) ++cin;
        }
    }
    {
        uint32_t inc = cin;
#pragma unroll
        for (int d = 1; d < 64; d <<= 1) {
            uint32_t t2 = __shfl_up(inc, d, 64);
            if (lane >= d) inc += t2;
        }
        if (lane == 63) wtot[wv] = inc;
        __syncthreads();
        uint32_t woff = 0;
        for (int w = 0; w < wv; ++w) woff += wtot[w];
        const uint32_t myoff = woff + inc - cin;
        if (tid == 0) {
            uint32_t tot = 0;
            for (int w = 0; w < 16; ++w) tot += wtot[w];
            sBase = tot ? atomicAdd(gCnt, tot) : 0u;
        }
        __syncthreads();
        if (cin) {
            uint32_t o = sBase + myoff;
            for (int rg = 0; rg < 2; ++rg) {
                const int r  = rsub + rg * 4;
                const int qr = q0 + r;
                if (sL[n] == sL[qr]) continue;
                const float dqn = sD[r][n];
                const int pc = min(pcnt[r], PMAX);
                for (int ip = 0; ip < pc; ++ip) {
                    const uint32_t bits =
                        __float_as_uint(fmaxf(pbase[r][ip] - dqn, 0.0f));
                    if ((bits >> 21) == s0) {
                        if (o < BUFCAP) st_rlx32(&buf[o], bits);
                        ++o;
                    }
                }
            }
        }
    }
    // block-reduce sumA -> one gSum RMW per block
#pragma unroll
    for (int off = 32; off > 0; off >>= 1)
        sumA += __shfl_down((unsigned long long)sumA, off, 64);
    if (lane == 0) usum[wv] = sumA;
    __syncthreads();
    if (tid == 0) {
        unsigned long long bt = 0;
        for (int w = 0; w < 16; ++w) bt += usum[w];
        if (bt) atomicAdd((unsigned long long*)gSum, bt);
    }
    __syncthreads();   // drain all waves' global ops before arrival
    if (tid == 0) {
        const uint32_t old =
            __hip_atomic_fetch_add(cnt1, 1u, __ATOMIC_ACQ_REL, SC_AGENT);
        sFin = (old == NBLK - 1) ? 1 : 0;
    }
    __syncthreads();
    if (!sFin) return;   // 31 blocks exit; no spinning

    // ================= finalizer (last arriver) =================
    const uint32_t nbuf = min(ld_rlx32(gCnt), BUFCAP);

    // level 2: bits[20:10] count+sum hists from buf
    for (int i = tid; i < 2048; i += NT) { sh[0][i] = 0; ssum[i] = 0ull; }
    __syncthreads();
    for (uint32_t i = (uint32_t)tid; i < nbuf; i += NT) {
        const uint32_t b = ld_rlx32(&buf[i]);
        const uint32_t b2 = (b >> 10) & 0x7FFu;
        atomicAdd(&sh[0][b2], 1u);
        atomicAdd(&ssum[b2], (unsigned long long)fixv(__uint_as_float(b)));
    }
    __syncthreads();
    selstep<2, false>(sh[0], needed0, wtot, res, tid);
    const uint32_t s1      = res[0];
    const uint32_t needed1 = res[1];
    {
        uint64_t sb = 0;
#pragma unroll
        for (int k = 0; k < 2; ++k) {
            const uint32_t b = (uint32_t)tid * 2u + (uint32_t)k;
            if (b > s1) sb += ssum[b];
        }
#pragma unroll
        for (int off = 32; off > 0; off >>= 1)
            sb += __shfl_down((unsigned long long)sb, off, 64);
        if (lane == 0) usum[wv] = sb;
        __syncthreads();
        if (tid == 0) {
            unsigned long long t = 0;
            for (int w = 0; w < 16; ++w) t += usum[w];
            sAcc2 = t;
        }
    }
    __syncthreads();

    // level 3: bits[9:0] within (s0,s1)
    for (int i = tid; i < 1024; i += NT) { sh[0][i] = 0; ssum[i] = 0ull; }
    __syncthreads();
    for (uint32_t i = (uint32_t)tid; i < nbuf; i += NT) {
        const uint32_t b = ld_rlx32(&buf[i]);
        if (((b >> 10) & 0x7FFu) == s1) {
            const uint32_t b3 = b & 0x3FFu;
            atomicAdd(&sh[0][b3], 1u);
            atomicAdd(&ssum[b3], (unsigned long long)fixv(__uint_as_float(b)));
        }
    }
    __syncthreads();
    selstep<1, false>(sh[0], needed1, wtot, res, tid);
    const uint32_t s2      = res[0];
    const uint32_t needed2 = res[1];
    const uint32_t T = (s0 << 21) | (s1 << 10) | s2;
    {
        uint64_t sb = (tid < 1024 && (uint32_t)tid > s2) ? ssum[tid] : 0ull;
#pragma unroll
        for (int off = 32; off > 0; off >>= 1)
            sb += __shfl_down((unsigned long long)sb, off, 64);
        if (lane == 0) usum[wv] = sb;
        __syncthreads();
        if (tid == 0) {
            unsigned long long t = 0;
            for (int w = 0; w < 16; ++w) t += usum[w];
            const uint64_t total = t + sAcc2 + ld_rlx64(gSum);
            const double tval = (double)__uint_as_float(T);
            const double loss = ((double)total * (1.0 / FIX_SCALE) +
                                 (double)needed2 * tval) / (double)TOPK;
            out[0] = (float)loss;
        }
    }
}

extern "C" void kernel_launch(void* const* d_in, const int* in_sizes, int n_in,
                              void* d_out, int out_size, void* d_ws, size_t ws_size,
                              hipStream_t stream) {
    const float* x   = (const float*)d_in[0];
    const int*   lab = (const int*)d_in[1];
    float*       out = (float*)d_out;
    uint32_t*    gws = (uint32_t*)d_ws;

    hipMemsetAsync(gws, 0, WS_ZERO_BYTES, stream);

    void* args[] = {(void*)&x, (void*)&lab, (void*)&gws, (void*)&out};
    hipLaunchCooperativeKernel((const void*)triplet_kernel, dim3(NBLK), dim3(NT),
                               args, 0, stream);
}

// Round 9
// 88.521 us; speedup vs baseline: 1.5002x; 1.2564x over previous
//
#include <hip/hip_runtime.h>
#include <stdint.h>

#define B 256
#define DIM 512
#define TOPK 4096
#define MARGIN 0.2f
#define SC_AGENT __HIP_MEMORY_SCOPE_AGENT
#define NBLK 32
#define RPB 8               /* q-rows per block */
#define NT 1024             /* threads per block */
#define PMAX 64
#define BUFCAP 60000u
#define FIX_SCALE 4294967296.0   /* 2^32 */

// ---------------- ws layout (zeroed region per call) ----------------
// ghA u32[2048] @ 0   gFlags u32[32] @ 8192   gCnt @ 8320   cnt1 @ 8324
// gSum u64 @ 8328     buf u32[BUFCAP] @ 8336 (not zeroed)
#define WS_ZERO_BYTES 8336

__device__ __forceinline__ uint32_t ld_rlx32(const uint32_t* p) {
    return __hip_atomic_load(p, __ATOMIC_RELAXED, SC_AGENT);
}
__device__ __forceinline__ uint64_t ld_rlx64(const uint64_t* p) {
    return __hip_atomic_load(p, __ATOMIC_RELAXED, SC_AGENT);
}
__device__ __forceinline__ void st_rlx32(uint32_t* p, uint32_t v) {
    __hip_atomic_store(p, v, __ATOMIC_RELAXED, SC_AGENT);
}
__device__ __forceinline__ uint64_t fixv(float v) {
    return (uint64_t)((double)v * FIX_SCALE + 0.5);
}

// Radix-select step over NT*PER buckets, descending. Thread tid owns chunk
// (NT-1-tid); inclusive shuffle-scan over tid == suffix sums over buckets.
// Exactly one thread writes res[0]=bucket, res[1]=remaining needed.
template <int PER, bool GLOBAL>
__device__ void selstep(const uint32_t* h, uint32_t needed,
                        uint32_t* wtot, uint32_t* res, int tid) {
    const int chunk = (NT - 1) - tid;
    uint32_t vals[PER];
    uint32_t v = 0;
#pragma unroll
    for (int k = 0; k < PER; ++k) {
        vals[k] = GLOBAL ? ld_rlx32(&h[chunk * PER + k]) : h[chunk * PER + k];
        v += vals[k];
    }
    uint32_t s = v;
    const int lane = tid & 63, wv = tid >> 6;
#pragma unroll
    for (int d = 1; d < 64; d <<= 1) {
        uint32_t t = __shfl_up(s, d, 64);
        if (lane >= d) s += t;
    }
    if (lane == 63) wtot[wv] = s;
    __syncthreads();
    uint32_t off = 0;
    for (int w = 0; w < wv; ++w) off += wtot[w];
    s += off;                       // count in buckets >= chunk*PER
    const uint32_t excl = s - v;    // count strictly above own chunk
    if (excl < needed && needed <= s) {
        uint32_t cum = excl;
#pragma unroll
        for (int k = PER - 1; k >= 0; --k) {
            const uint32_t hv = vals[k];
            if (cum + hv >= needed) {
                res[0] = (uint32_t)(chunk * PER + k);
                res[1] = needed - cum;
                break;
            }
            cum += hv;
        }
    }
    __syncthreads();
}

__global__ void __launch_bounds__(NT, 1)
triplet_kernel(const float* __restrict__ x, const int* __restrict__ lab,
               uint32_t* __restrict__ gws, float* __restrict__ out) {
    uint32_t* ghA    = gws;
    uint32_t* gFlags = gws + 2048;
    uint32_t* gCnt   = gws + 2080;
    uint32_t* cnt1   = gws + 2081;
    uint64_t* gSum   = (uint64_t*)(gws + 2082);   // byte 8328, 8-aligned
    uint32_t* buf    = gws + 2084;                // byte 8336

    __shared__ float    xi[RPB * DIM];            // 16 KB
    __shared__ float    sD[RPB][B];               // 8 KB
    __shared__ float    pbase[RPB][PMAX];         // 2 KB
    __shared__ int      pcnt[RPB];
    __shared__ int      sL[B];
    __shared__ uint32_t sh[4][2048];              // 32 KB privatized count hists
    __shared__ unsigned long long ssum[2048];     // 16 KB (finalizer sums)
    __shared__ uint32_t wtot[16];
    __shared__ uint32_t res[2];
    __shared__ unsigned long long usum[16];
    __shared__ unsigned long long sAcc2;
    __shared__ uint32_t sBase;
    __shared__ int      sFin;

    const int bid = blockIdx.x, tid = threadIdx.x;
    const int lane = tid & 63, wv = tid >> 6;
    const int copy = wv & 3;
    const int q0 = bid * RPB;
    const int n = tid & 255;
    const int rsub = tid >> 8;                    // 0..3

    // ---- stage labels, q-rows, zero LDS hists ----
    if (tid < B) sL[tid] = lab[tid];
    for (int i = tid; i < RPB * DIM; i += NT) xi[i] = x[q0 * DIM + i];
    for (int i = tid; i < 4 * 2048; i += NT) ((uint32_t*)sh)[i] = 0;
    if (tid < RPB) pcnt[tid] = 0;
    __syncthreads();

    // ---- D rows, wave-per-column (coalesced xj, conflict-free xi) ----
    // wave wv owns columns n = wv*16 .. +15. For each column, 64 lanes read
    // consecutive float2 of row n (512B/instr, coalesced); xi float2 from LDS
    // at lane*8B stride (2-way bank alias = free). Butterfly-reduce 8 accs.
    for (int c = 0; c < 16; ++c) {
        const int col = wv * 16 + c;
        const float2* xj2 = (const float2*)(x + col * DIM);
        float acc[8];
#pragma unroll
        for (int r = 0; r < 8; ++r) acc[r] = 0.f;
#pragma unroll
        for (int t = 0; t < 4; ++t) {
            const float2 bv = xj2[t * 64 + lane];
#pragma unroll
            for (int r = 0; r < 8; ++r) {
                const float2 av =
                    *(const float2*)&xi[r * DIM + (t * 64 + lane) * 2];
                const float d0 = av.x - bv.x;
                const float d1 = av.y - bv.y;
                acc[r] += d0 * d0 + d1 * d1;
            }
        }
#pragma unroll
        for (int off = 32; off > 0; off >>= 1) {
#pragma unroll
            for (int r = 0; r < 8; ++r)
                acc[r] += __shfl_xor(acc[r], off, 64);
        }
        if (lane < 8) sD[lane][col] = acc[lane];
    }
    __syncthreads();

    // ---- compact valid positives per row (order-free: downstream commutes) ----
    if (tid < B) {
        const int p = tid;
        for (int r = 0; r < RPB; ++r) {
            const int qr = q0 + r;
            if (p < qr && sL[p] == sL[qr]) {
                const int pos = atomicAdd(&pcnt[r], 1);
                if (pos < PMAX) pbase[r][pos] = sD[r][p] + MARGIN;
            }
        }
    }
    __syncthreads();

    // ---- phase 1: count hist over bits[31:21]; zeros counted in registers ----
    {
        uint32_t zc = 0;
        for (int rg = 0; rg < 2; ++rg) {
            const int r  = rsub + rg * 4;
            const int qr = q0 + r;
            if (sL[n] == sL[qr]) continue;        // n invalid for this row
            const float dqn = sD[r][n];
            const int pc = min(pcnt[r], PMAX);
            for (int ip = 0; ip < pc; ++ip) {
                const float v = fmaxf(pbase[r][ip] - dqn, 0.0f);
                if (v == 0.0f) { ++zc; continue; }  // bucket 0; no atomic
                atomicAdd(&sh[copy][__float_as_uint(v) >> 21], 1u);
            }
        }
#pragma unroll
        for (int off = 32; off > 0; off >>= 1) zc += __shfl_down(zc, off, 64);
        if (lane == 0 && zc) atomicAdd(&sh[copy][0], zc);
    }
    __syncthreads();
    for (int i = tid; i < 2048; i += NT) {
        const uint32_t c = sh[0][i] + sh[1][i] + sh[2][i] + sh[3][i];
        if (c) atomicAdd(&ghA[i], c);
    }
    __syncthreads();   // all waves' global atomics issued before flag
    if (tid == 0) __hip_atomic_store(&gFlags[bid], 1u, __ATOMIC_RELEASE, SC_AGENT);

    // ---- single grid barrier: poll 32 flags ----
    for (;;) {
        const uint32_t f = (tid < NBLK) ? ld_rlx32(&gFlags[tid]) : 1u;
        if (__syncthreads_count(f != 0) == NT) break;
        __builtin_amdgcn_s_sleep(2);
    }
    asm volatile("" ::: "memory");

    // ---- redundant select of s0 (every block; no publish round-trip) ----
    selstep<2, true>(ghA, (uint32_t)TOPK, wtot, res, tid);
    const uint32_t s0      = res[0];
    const uint32_t needed0 = res[1];

    // ---- phase 2: register sum above s0 + append in-bucket values ----
    uint64_t sumA = 0;
    uint32_t cin  = 0;
    for (int rg = 0; rg < 2; ++rg) {
        const int r  = rsub + rg * 4;
        const int qr = q0 + r;
        if (sL[n] == sL[qr]) continue;
        const float dqn = sD[r][n];
        const int pc = min(pcnt[r], PMAX);
        for (int ip = 0; ip < pc; ++ip) {
            const float v = fmaxf(pbase[r][ip] - dqn, 0.0f);
            const uint32_t bk = __float_as_uint(v) >> 21;
            if (bk > s0) sumA += fixv(v);
            else if (bk == s0) ++cin;
        }
    }
    {
        uint32_t inc = cin;
#pragma unroll
        for (int d = 1; d < 64; d <<= 1) {
            uint32_t t2 = __shfl_up(inc, d, 64);
            if (lane >= d) inc += t2;
        }
        if (lane == 63) wtot[wv] = inc;
        __syncthreads();
        uint32_t woff = 0;
        for (int w = 0; w < wv; ++w) woff += wtot[w];
        const uint32_t myoff = woff + inc - cin;
        if (tid == 0) {
            uint32_t tot = 0;
            for (int w = 0; w < 16; ++w) tot += wtot[w];
            sBase = tot ? atomicAdd(gCnt, tot) : 0u;
        }
        __syncthreads();
        if (cin) {
            uint32_t o = sBase + myoff;
            for (int rg = 0; rg < 2; ++rg) {
                const int r  = rsub + rg * 4;
                const int qr = q0 + r;
                if (sL[n] == sL[qr]) continue;
                const float dqn = sD[r][n];
                const int pc = min(pcnt[r], PMAX);
                for (int ip = 0; ip < pc; ++ip) {
                    const uint32_t bits =
                        __float_as_uint(fmaxf(pbase[r][ip] - dqn, 0.0f));
                    if ((bits >> 21) == s0) {
                        if (o < BUFCAP) st_rlx32(&buf[o], bits);
                        ++o;
                    }
                }
            }
        }
    }
    // block-reduce sumA -> one gSum RMW per block
#pragma unroll
    for (int off = 32; off > 0; off >>= 1)
        sumA += __shfl_down((unsigned long long)sumA, off, 64);
    if (lane == 0) usum[wv] = sumA;
    __syncthreads();
    if (tid == 0) {
        unsigned long long bt = 0;
        for (int w = 0; w < 16; ++w) bt += usum[w];
        if (bt) atomicAdd((unsigned long long*)gSum, bt);
    }
    __syncthreads();   // drain all waves' global ops before arrival
    if (tid == 0) {
        const uint32_t old =
            __hip_atomic_fetch_add(cnt1, 1u, __ATOMIC_ACQ_REL, SC_AGENT);
        sFin = (old == NBLK - 1) ? 1 : 0;
    }
    __syncthreads();
    if (!sFin) return;   // 31 blocks exit; no spinning

    // ================= finalizer (last arriver) =================
    const uint32_t nbuf = min(ld_rlx32(gCnt), BUFCAP);

    // level 2: bits[20:10] count+sum hists from buf
    for (int i = tid; i < 2048; i += NT) { sh[0][i] = 0; ssum[i] = 0ull; }
    __syncthreads();
    for (uint32_t i = (uint32_t)tid; i < nbuf; i += NT) {
        const uint32_t b = ld_rlx32(&buf[i]);
        const uint32_t b2 = (b >> 10) & 0x7FFu;
        atomicAdd(&sh[0][b2], 1u);
        atomicAdd(&ssum[b2], (unsigned long long)fixv(__uint_as_float(b)));
    }
    __syncthreads();
    selstep<2, false>(sh[0], needed0, wtot, res, tid);
    const uint32_t s1      = res[0];
    const uint32_t needed1 = res[1];
    {
        uint64_t sb = 0;
#pragma unroll
        for (int k = 0; k < 2; ++k) {
            const uint32_t b = (uint32_t)tid * 2u + (uint32_t)k;
            if (b > s1) sb += ssum[b];
        }
#pragma unroll
        for (int off = 32; off > 0; off >>= 1)
            sb += __shfl_down((unsigned long long)sb, off, 64);
        if (lane == 0) usum[wv] = sb;
        __syncthreads();
        if (tid == 0) {
            unsigned long long t = 0;
            for (int w = 0; w < 16; ++w) t += usum[w];
            sAcc2 = t;
        }
    }
    __syncthreads();

    // level 3: bits[9:0] within (s0,s1)
    for (int i = tid; i < 1024; i += NT) { sh[0][i] = 0; ssum[i] = 0ull; }
    __syncthreads();
    for (uint32_t i = (uint32_t)tid; i < nbuf; i += NT) {
        const uint32_t b = ld_rlx32(&buf[i]);
        if (((b >> 10) & 0x7FFu) == s1) {
            const uint32_t b3 = b & 0x3FFu;
            atomicAdd(&sh[0][b3], 1u);
            atomicAdd(&ssum[b3], (unsigned long long)fixv(__uint_as_float(b)));
        }
    }
    __syncthreads();
    selstep<1, false>(sh[0], needed1, wtot, res, tid);
    const uint32_t s2      = res[0];
    const uint32_t needed2 = res[1];
    const uint32_t T = (s0 << 21) | (s1 << 10) | s2;
    {
        uint64_t sb = (tid < 1024 && (uint32_t)tid > s2) ? ssum[tid] : 0ull;
#pragma unroll
        for (int off = 32; off > 0; off >>= 1)
            sb += __shfl_down((unsigned long long)sb, off, 64);
        if (lane == 0) usum[wv] = sb;
        __syncthreads();
        if (tid == 0) {
            unsigned long long t = 0;
            for (int w = 0; w < 16; ++w) t += usum[w];
            const uint64_t total = t + sAcc2 + ld_rlx64(gSum);
            const double tval = (double)__uint_as_float(T);
            const double loss = ((double)total * (1.0 / FIX_SCALE) +
                                 (double)needed2 * tval) / (double)TOPK;
            out[0] = (float)loss;
        }
    }
}

extern "C" void kernel_launch(void* const* d_in, const int* in_sizes, int n_in,
                              void* d_out, int out_size, void* d_ws, size_t ws_size,
                              hipStream_t stream) {
    const float* x   = (const float*)d_in[0];
    const int*   lab = (const int*)d_in[1];
    float*       out = (float*)d_out;
    uint32_t*    gws = (uint32_t*)d_ws;

    hipMemsetAsync(gws, 0, WS_ZERO_BYTES, stream);

    void* args[] = {(void*)&x, (void*)&lab, (void*)&gws, (void*)&out};
    hipLaunchCooperativeKernel((const void*)triplet_kernel, dim3(NBLK), dim3(NT),
                               args, 0, stream);
}

// Round 10
// 82.084 us; speedup vs baseline: 1.6179x; 1.0784x over previous
//
#include <hip/hip_runtime.h>
#include <stdint.h>

#define B 256
#define DIM 512
#define TOPK 4096
#define MARGIN 0.2f
#define SC_AGENT __HIP_MEMORY_SCOPE_AGENT
#define PMAX 64
#define BUFCAP 60000u
#define FIX_SCALE 4294967296.0   /* 2^32 */

// ---------------- ws layout (zeroed region per call) ----------------
// ghA u32[2048] @ 0   gFlags u32[256] @ 8192   gCnt @ 9216   cnt1 @ 9220
// gSum u64 @ 9224     buf u32[BUFCAP] @ 9232 (not zeroed)
#define WS_ZERO_BYTES 9232

__device__ __forceinline__ uint32_t ld_rlx32(const uint32_t* p) {
    return __hip_atomic_load(p, __ATOMIC_RELAXED, SC_AGENT);
}
__device__ __forceinline__ uint64_t ld_rlx64(const uint64_t* p) {
    return __hip_atomic_load(p, __ATOMIC_RELAXED, SC_AGENT);
}
__device__ __forceinline__ void st_rlx32(uint32_t* p, uint32_t v) {
    __hip_atomic_store(p, v, __ATOMIC_RELAXED, SC_AGENT);
}
__device__ __forceinline__ uint64_t fixv(float v) {
    return (uint64_t)((double)v * FIX_SCALE + 0.5);
}

// Radix-select step over 256*PER buckets, descending. Thread tid owns chunk
// (255-tid); inclusive shuffle-scan over tid == suffix sums over buckets.
// Exactly one thread writes res[0]=bucket, res[1]=remaining needed.
template <int PER, bool GLOBAL>
__device__ void selstep(const uint32_t* h, uint32_t needed,
                        uint32_t* wtot, uint32_t* res, int tid) {
    const int chunk = 255 - tid;
    uint32_t vals[PER];
    uint32_t v = 0;
#pragma unroll
    for (int k = 0; k < PER; ++k) {
        vals[k] = GLOBAL ? ld_rlx32(&h[chunk * PER + k]) : h[chunk * PER + k];
        v += vals[k];
    }
    uint32_t s = v;
    const int lane = tid & 63, wv = tid >> 6;
#pragma unroll
    for (int d = 1; d < 64; d <<= 1) {
        uint32_t t = __shfl_up(s, d, 64);
        if (lane >= d) s += t;
    }
    if (lane == 63) wtot[wv] = s;
    __syncthreads();
    uint32_t off = 0;
    for (int w = 0; w < wv; ++w) off += wtot[w];
    s += off;                       // count in buckets >= chunk*PER
    const uint32_t excl = s - v;    // count strictly above own chunk
    if (excl < needed && needed <= s) {
        uint32_t cum = excl;
#pragma unroll
        for (int k = PER - 1; k >= 0; --k) {
            const uint32_t hv = vals[k];
            if (cum + hv >= needed) {
                res[0] = (uint32_t)(chunk * PER + k);
                res[1] = needed - cum;
                break;
            }
            cum += hv;
        }
    }
    __syncthreads();
}

__global__ void __launch_bounds__(256, 1)
triplet_kernel(const float* __restrict__ x, const int* __restrict__ lab,
               uint32_t* __restrict__ gws, float* __restrict__ out) {
    uint32_t* ghA    = gws;
    uint32_t* gFlags = gws + 2048;
    uint32_t* gCnt   = gws + 2304;
    uint32_t* cnt1   = gws + 2305;
    uint64_t* gSum   = (uint64_t*)(gws + 2306);   // byte 9224, 8-aligned
    uint32_t* buf    = gws + 2308;                // byte 9232

    __shared__ float    xq[DIM];                  // 2 KB: this block's q-row
    __shared__ float    sD[B];                    // 1 KB
    __shared__ int      sL[B];                    // 1 KB
    __shared__ float    pbase[PMAX];
    __shared__ int      wcnt[4];
    __shared__ uint32_t wtot[4];
    __shared__ uint32_t res[2];
    __shared__ unsigned long long usum[4];
    __shared__ uint32_t sh[4][2048];              // 32 KB wave-privatized hists
    __shared__ unsigned long long ssum[2048];     // 16 KB finalizer sum-hist
    __shared__ unsigned long long sAcc2;
    __shared__ uint32_t sBase;
    __shared__ int      pcnt_s, sFin;

    const int q = blockIdx.x, tid = threadIdx.x;
    const int lane = tid & 63, wv = tid >> 6;

    // ---- stage labels + q-row; zero privatized hists ----
    sL[tid] = lab[tid];
    xq[tid]       = x[q * DIM + tid];
    xq[tid + 256] = x[q * DIM + 256 + tid];
    for (int i = tid; i < 4 * 2048; i += 256) ((uint32_t*)sh)[i] = 0;
    __syncthreads();

    // ---- D row q, wave-per-column (coalesced xj; xq hoisted to registers) ----
    {
        float2 av[4];
#pragma unroll
        for (int t = 0; t < 4; ++t)
            av[t] = *(const float2*)&xq[(t * 64 + lane) * 2];
#pragma unroll 2
        for (int c = 0; c < 64; ++c) {
            const int col = wv * 64 + c;
            const float2* xj2 = (const float2*)(x + col * DIM);
            float acc = 0.f;
#pragma unroll
            for (int t = 0; t < 4; ++t) {
                const float2 bv = xj2[t * 64 + lane];
                const float d0 = av[t].x - bv.x;
                const float d1 = av[t].y - bv.y;
                acc += d0 * d0 + d1 * d1;
            }
#pragma unroll
            for (int off = 32; off > 0; off >>= 1)
                acc += __shfl_xor(acc, off, 64);
            if (lane == 0) sD[col] = acc;
        }
    }
    __syncthreads();

    // ---- compact valid positives (p < q, same label), ballot order ----
    const int lq = sL[q];
    {
        const bool pred = (tid < q) && (sL[tid] == lq);
        const uint64_t mask = __ballot(pred);
        if (lane == 0) wcnt[wv] = __popcll(mask);
        __syncthreads();
        int off = 0;
        for (int w = 0; w < wv; ++w) off += wcnt[w];
        if (pred) {
            const int pos = off + __popcll(mask & ((1ull << lane) - 1));
            if (pos < PMAX) pbase[pos] = sD[tid] + MARGIN;
        }
        if (tid == 0) {
            const int t = wcnt[0] + wcnt[1] + wcnt[2] + wcnt[3];
            pcnt_s = t < PMAX ? t : PMAX;
        }
    }
    __syncthreads();
    const int   pcnt   = pcnt_s;
    const bool  nvalid = (sL[tid] != lq);
    const float dqn    = sD[tid];

    // ---- phase 1: hist over bits[31:21]; zeros in registers, wave-private ----
    {
        uint32_t zc = 0;
        if (nvalid) {
            for (int ip = 0; ip < pcnt; ++ip) {
                const float v = fmaxf(pbase[ip] - dqn, 0.0f);
                if (v == 0.0f) { ++zc; continue; }      // bucket 0; no atomic
                atomicAdd(&sh[wv][__float_as_uint(v) >> 21], 1u);
            }
        }
#pragma unroll
        for (int off = 32; off > 0; off >>= 1) zc += __shfl_down(zc, off, 64);
        if (lane == 0 && zc) atomicAdd(&sh[wv][0], zc);
    }
    __syncthreads();
    for (int i = tid; i < 2048; i += 256) {
        const uint32_t c = sh[0][i] + sh[1][i] + sh[2][i] + sh[3][i];
        if (c) atomicAdd(&ghA[i], c);
    }
    __syncthreads();   // all waves' global atomics retired before flag
    if (tid == 0) __hip_atomic_store(&gFlags[q], 1u, __ATOMIC_RELEASE, SC_AGENT);

    // ---- single grid barrier: wave 0 polls all 256 flags (4 per lane) ----
    if (wv == 0) {
        for (;;) {
            int ok = 1;
#pragma unroll
            for (int k = 0; k < 4; ++k)
                ok &= (ld_rlx32(&gFlags[lane * 4 + k]) != 0) ? 1 : 0;
            if (__all(ok)) break;
            __builtin_amdgcn_s_sleep(8);
        }
    }
    __syncthreads();
    asm volatile("" ::: "memory");

    // ---- redundant select of s0 (every block; no publish round-trip) ----
    selstep<8, true>(ghA, (uint32_t)TOPK, wtot, res, tid);
    const uint32_t s0      = res[0];
    const uint32_t needed0 = res[1];

    // ---- phase 2: register sum above s0 + append in-bucket values ----
    uint64_t sumA = 0;
    uint32_t cin  = 0;
    if (nvalid) {
        for (int ip = 0; ip < pcnt; ++ip) {
            const float v = fmaxf(pbase[ip] - dqn, 0.0f);
            const uint32_t bk = __float_as_uint(v) >> 21;
            if (bk > s0) sumA += fixv(v);
            else if (bk == s0) ++cin;
        }
    }
    {
        uint32_t inc = cin;
#pragma unroll
        for (int d = 1; d < 64; d <<= 1) {
            uint32_t t2 = __shfl_up(inc, d, 64);
            if (lane >= d) inc += t2;
        }
        if (lane == 63) wtot[wv] = inc;
        __syncthreads();
        uint32_t woff = 0;
        for (int w = 0; w < wv; ++w) woff += wtot[w];
        const uint32_t myoff = woff + inc - cin;
        if (tid == 0) {
            const uint32_t tot = wtot[0] + wtot[1] + wtot[2] + wtot[3];
            sBase = tot ? atomicAdd(gCnt, tot) : 0u;
        }
        __syncthreads();
        if (cin) {
            uint32_t o = sBase + myoff;
            for (int ip = 0; ip < pcnt; ++ip) {
                const uint32_t bits =
                    __float_as_uint(fmaxf(pbase[ip] - dqn, 0.0f));
                if ((bits >> 21) == s0) {
                    if (o < BUFCAP) st_rlx32(&buf[o], bits);
                    ++o;
                }
            }
        }
    }
    // block-reduce sumA -> one gSum RMW per block
#pragma unroll
    for (int off = 32; off > 0; off >>= 1)
        sumA += __shfl_down((unsigned long long)sumA, off, 64);
    if (lane == 0) usum[wv] = sumA;
    __syncthreads();
    if (tid == 0) {
        const unsigned long long bt = usum[0] + usum[1] + usum[2] + usum[3];
        if (bt) atomicAdd((unsigned long long*)gSum, bt);
    }
    __syncthreads();   // drain all waves' global ops before arrival
    if (tid == 0) {
        const uint32_t old =
            __hip_atomic_fetch_add(cnt1, 1u, __ATOMIC_ACQ_REL, SC_AGENT);
        sFin = (old == B - 1) ? 1 : 0;
    }
    __syncthreads();
    if (!sFin) return;   // 255 blocks exit; no spinning

    // ================= finalizer (last arriver) =================
    const uint32_t nbuf = min(ld_rlx32(gCnt), BUFCAP);

    // level 2: bits[20:10] count+sum hists from buf
    for (int i = tid; i < 2048; i += 256) { sh[0][i] = 0; ssum[i] = 0ull; }
    __syncthreads();
    for (uint32_t i = (uint32_t)tid; i < nbuf; i += 256) {
        const uint32_t b = ld_rlx32(&buf[i]);
        const uint32_t b2 = (b >> 10) & 0x7FFu;
        atomicAdd(&sh[0][b2], 1u);
        atomicAdd(&ssum[b2], (unsigned long long)fixv(__uint_as_float(b)));
    }
    __syncthreads();
    selstep<8, false>(sh[0], needed0, wtot, res, tid);
    const uint32_t s1      = res[0];
    const uint32_t needed1 = res[1];
    {
        uint64_t sb = 0;
#pragma unroll
        for (int k = 0; k < 8; ++k) {
            const uint32_t b = (uint32_t)tid * 8u + (uint32_t)k;
            if (b > s1) sb += ssum[b];
        }
#pragma unroll
        for (int off = 32; off > 0; off >>= 1)
            sb += __shfl_down((unsigned long long)sb, off, 64);
        if (lane == 0) usum[wv] = sb;
        __syncthreads();
        if (tid == 0) sAcc2 = usum[0] + usum[1] + usum[2] + usum[3];
    }
    __syncthreads();

    // level 3: bits[9:0] within (s0,s1)
    for (int i = tid; i < 1024; i += 256) { sh[0][i] = 0; ssum[i] = 0ull; }
    __syncthreads();
    for (uint32_t i = (uint32_t)tid; i < nbuf; i += 256) {
        const uint32_t b = ld_rlx32(&buf[i]);
        if (((b >> 10) & 0x7FFu) == s1) {
            const uint32_t b3 = b & 0x3FFu;
            atomicAdd(&sh[0][b3], 1u);
            atomicAdd(&ssum[b3], (unsigned long long)fixv(__uint_as_float(b)));
        }
    }
    __syncthreads();
    selstep<4, false>(sh[0], needed1, wtot, res, tid);
    const uint32_t s2      = res[0];
    const uint32_t needed2 = res[1];
    const uint32_t T = (s0 << 21) | (s1 << 10) | s2;
    {
        uint64_t sb = 0;
#pragma unroll
        for (int k = 0; k < 4; ++k) {
            const uint32_t b = (uint32_t)tid * 4u + (uint32_t)k;
            if (b > s2) sb += ssum[b];
        }
#pragma unroll
        for (int off = 32; off > 0; off >>= 1)
            sb += __shfl_down((unsigned long long)sb, off, 64);
        if (lane == 0) usum[wv] = sb;
        __syncthreads();
        if (tid == 0) {
            const uint64_t total =
                usum[0] + usum[1] + usum[2] + usum[3] + sAcc2 + ld_rlx64(gSum);
            const double tval = (double)__uint_as_float(T);
            const double loss = ((double)total * (1.0 / FIX_SCALE) +
                                 (double)needed2 * tval) / (double)TOPK;
            out[0] = (float)loss;
        }
    }
}

extern "C" void kernel_launch(void* const* d_in, const int* in_sizes, int n_in,
                              void* d_out, int out_size, void* d_ws, size_t ws_size,
                              hipStream_t stream) {
    const float* x   = (const float*)d_in[0];
    const int*   lab = (const int*)d_in[1];
    float*       out = (float*)d_out;
    uint32_t*    gws = (uint32_t*)d_ws;

    hipMemsetAsync(gws, 0, WS_ZERO_BYTES, stream);

    void* args[] = {(void*)&x, (void*)&lab, (void*)&gws, (void*)&out};
    hipLaunchCooperativeKernel((const void*)triplet_kernel, dim3(B), dim3(256),
                               args, 0, stream);
}

// Round 11
// 73.958 us; speedup vs baseline: 1.7957x; 1.1099x over previous
//
#include <hip/hip_runtime.h>
#include <stdint.h>

#define B 256
#define DIM 512
#define TOPK 4096
#define MARGIN 0.2f
#define SC_AGENT __HIP_MEMORY_SCOPE_AGENT
#define PMAX 64
#define BUFCAP 60000u
#define FIX_SCALE 4294967296.0   /* 2^32 */

// ---------------- ws layout (zeroed region per call) ----------------
// ghA u32[2048] @ 0   gFlags u32[256] @ 8192   gCnt @ 9216   cnt1 @ 9220
// gSum u64 @ 9224     buf u32[BUFCAP] @ 9232 (not zeroed)
#define WS_ZERO_BYTES 9232

__device__ __forceinline__ uint32_t ld_rlx32(const uint32_t* p) {
    return __hip_atomic_load(p, __ATOMIC_RELAXED, SC_AGENT);
}
__device__ __forceinline__ uint64_t ld_rlx64(const uint64_t* p) {
    return __hip_atomic_load(p, __ATOMIC_RELAXED, SC_AGENT);
}
__device__ __forceinline__ void st_rlx32(uint32_t* p, uint32_t v) {
    __hip_atomic_store(p, v, __ATOMIC_RELAXED, SC_AGENT);
}
__device__ __forceinline__ uint64_t fixv(float v) {
    return (uint64_t)((double)v * FIX_SCALE + 0.5);
}

// Radix-select step over 256*PER buckets, descending. Thread tid owns chunk
// (255-tid); inclusive shuffle-scan over tid == suffix sums over buckets.
// Exactly one thread writes res[0]=bucket, res[1]=remaining needed.
template <int PER, bool GLOBAL>
__device__ void selstep(const uint32_t* h, uint32_t needed,
                        uint32_t* wtot, uint32_t* res, int tid) {
    const int chunk = 255 - tid;
    uint32_t vals[PER];
    uint32_t v = 0;
#pragma unroll
    for (int k = 0; k < PER; ++k) {
        vals[k] = GLOBAL ? ld_rlx32(&h[chunk * PER + k]) : h[chunk * PER + k];
        v += vals[k];
    }
    uint32_t s = v;
    const int lane = tid & 63, wv = tid >> 6;
#pragma unroll
    for (int d = 1; d < 64; d <<= 1) {
        uint32_t t = __shfl_up(s, d, 64);
        if (lane >= d) s += t;
    }
    if (lane == 63) wtot[wv] = s;
    __syncthreads();
    uint32_t off = 0;
    for (int w = 0; w < wv; ++w) off += wtot[w];
    s += off;                       // count in buckets >= chunk*PER
    const uint32_t excl = s - v;    // count strictly above own chunk
    if (excl < needed && needed <= s) {
        uint32_t cum = excl;
#pragma unroll
        for (int k = PER - 1; k >= 0; --k) {
            const uint32_t hv = vals[k];
            if (cum + hv >= needed) {
                res[0] = (uint32_t)(chunk * PER + k);
                res[1] = needed - cum;
                break;
            }
            cum += hv;
        }
    }
    __syncthreads();
}

__global__ void __launch_bounds__(256, 1)
triplet_kernel(const float* __restrict__ x, const int* __restrict__ lab,
               uint32_t* __restrict__ gws, float* __restrict__ out) {
    uint32_t* ghA    = gws;
    uint32_t* gFlags = gws + 2048;
    uint32_t* gCnt   = gws + 2304;
    uint32_t* cnt1   = gws + 2305;
    uint64_t* gSum   = (uint64_t*)(gws + 2306);   // byte 9224, 8-aligned
    uint32_t* buf    = gws + 2308;                // byte 9232

    __shared__ uint32_t sh[4][2048];              // 32 KB wave-privatized hists
    __shared__ unsigned long long ssum[2048];     // 16 KB finalizer sum-hist
    __shared__ float    sD[B];                    // 1 KB
    __shared__ int      sL[B];                    // 1 KB
    __shared__ float    pbase[PMAX];
    __shared__ int      wcnt[4];
    __shared__ uint32_t wtot[4];
    __shared__ uint32_t res[2];
    __shared__ unsigned long long usum[4];
    __shared__ unsigned long long sAcc2;
    __shared__ uint32_t sBase;
    __shared__ int      pcnt_s, sFin;

    const int q = blockIdx.x, tid = threadIdx.x;
    const int lane = tid & 63, wv = tid >> 6;

    // ---- P0: stage labels + q-row (alias sh as xi), per-thread-row D ----
    {
        float* xi = (float*)sh;                   // 512 floats = 2 KB
        for (int k = tid; k < DIM; k += 256) xi[k] = x[q * DIM + k];
        sL[tid] = lab[tid];
        __syncthreads();
        const float4* xj4 = (const float4*)(x + tid * DIM);
        float acc = 0.f;
#pragma unroll 4
        for (int k4 = 0; k4 < DIM / 4; ++k4) {
            float4 b = xj4[k4];
            float d0 = xi[k4 * 4 + 0] - b.x;
            float d1 = xi[k4 * 4 + 1] - b.y;
            float d2 = xi[k4 * 4 + 2] - b.z;
            float d3 = xi[k4 * 4 + 3] - b.w;
            acc += d0 * d0 + d1 * d1 + d2 * d2 + d3 * d3;
        }
        sD[tid] = acc;
    }
    __syncthreads();                              // xi reads done; sh reusable

    // ---- zero privatized hists + compact valid positives (ballot order) ----
    const int lq = sL[q];
    for (int i = tid; i < 4 * 2048; i += 256) ((uint32_t*)sh)[i] = 0;
    {
        const bool pred = (tid < q) && (sL[tid] == lq);
        const uint64_t mask = __ballot(pred);
        if (lane == 0) wcnt[wv] = __popcll(mask);
        __syncthreads();
        int off = 0;
        for (int w = 0; w < wv; ++w) off += wcnt[w];
        if (pred) {
            const int pos = off + __popcll(mask & ((1ull << lane) - 1));
            if (pos < PMAX) pbase[pos] = sD[tid] + MARGIN;
        }
        if (tid == 0) {
            const int t = wcnt[0] + wcnt[1] + wcnt[2] + wcnt[3];
            pcnt_s = t < PMAX ? t : PMAX;
        }
    }
    __syncthreads();
    const int   pcnt   = pcnt_s;
    const bool  nvalid = (sL[tid] != lq);
    const float dqn    = sD[tid];

    // ---- phase 1: hist over bits[31:21]; zeros in registers, wave-private ----
    {
        uint32_t zc = 0;
        if (nvalid) {
            for (int ip = 0; ip < pcnt; ++ip) {
                const float v = fmaxf(pbase[ip] - dqn, 0.0f);
                if (v == 0.0f) { ++zc; continue; }      // bucket 0; no atomic
                atomicAdd(&sh[wv][__float_as_uint(v) >> 21], 1u);
            }
        }
#pragma unroll
        for (int off = 32; off > 0; off >>= 1) zc += __shfl_down(zc, off, 64);
        if (lane == 0 && zc) atomicAdd(&sh[wv][0], zc);
    }
    __syncthreads();
    for (int i = tid; i < 2048; i += 256) {
        const uint32_t c = sh[0][i] + sh[1][i] + sh[2][i] + sh[3][i];
        if (c) atomicAdd(&ghA[i], c);
    }
    __syncthreads();   // all waves' global atomics retired before flag
    if (tid == 0) __hip_atomic_store(&gFlags[q], 1u, __ATOMIC_RELEASE, SC_AGENT);

    // ---- single grid barrier: all threads poll 256 flags (1 per thread) ----
    for (;;) {
        const uint32_t f = ld_rlx32(&gFlags[tid]);
        if (__syncthreads_count(f != 0) == B) break;
        __builtin_amdgcn_s_sleep(2);
    }
    asm volatile("" ::: "memory");

    // ---- redundant select of s0 (every block; no publish round-trip) ----
    selstep<8, true>(ghA, (uint32_t)TOPK, wtot, res, tid);
    const uint32_t s0      = res[0];
    const uint32_t needed0 = res[1];

    // ---- phase 2: register sum above s0 + append in-bucket values ----
    uint64_t sumA = 0;
    uint32_t cin  = 0;
    if (nvalid) {
        for (int ip = 0; ip < pcnt; ++ip) {
            const float v = fmaxf(pbase[ip] - dqn, 0.0f);
            const uint32_t bk = __float_as_uint(v) >> 21;
            if (bk > s0) sumA += fixv(v);
            else if (bk == s0) ++cin;
        }
    }
    {
        uint32_t inc = cin;
#pragma unroll
        for (int d = 1; d < 64; d <<= 1) {
            uint32_t t2 = __shfl_up(inc, d, 64);
            if (lane >= d) inc += t2;
        }
        if (lane == 63) wtot[wv] = inc;
        __syncthreads();
        uint32_t woff = 0;
        for (int w = 0; w < wv; ++w) woff += wtot[w];
        const uint32_t myoff = woff + inc - cin;
        if (tid == 0) {
            const uint32_t tot = wtot[0] + wtot[1] + wtot[2] + wtot[3];
            sBase = tot ? atomicAdd(gCnt, tot) : 0u;
        }
        __syncthreads();
        if (cin) {
            uint32_t o = sBase + myoff;
            for (int ip = 0; ip < pcnt; ++ip) {
                const uint32_t bits =
                    __float_as_uint(fmaxf(pbase[ip] - dqn, 0.0f));
                if ((bits >> 21) == s0) {
                    if (o < BUFCAP) st_rlx32(&buf[o], bits);
                    ++o;
                }
            }
        }
    }
    // block-reduce sumA -> one gSum RMW per block
#pragma unroll
    for (int off = 32; off > 0; off >>= 1)
        sumA += __shfl_down((unsigned long long)sumA, off, 64);
    if (lane == 0) usum[wv] = sumA;
    __syncthreads();
    if (tid == 0) {
        const unsigned long long bt = usum[0] + usum[1] + usum[2] + usum[3];
        if (bt) atomicAdd((unsigned long long*)gSum, bt);
    }
    __syncthreads();   // drain all waves' global ops before arrival
    if (tid == 0) {
        const uint32_t old =
            __hip_atomic_fetch_add(cnt1, 1u, __ATOMIC_ACQ_REL, SC_AGENT);
        sFin = (old == B - 1) ? 1 : 0;
    }
    __syncthreads();
    if (!sFin) return;   // 255 blocks exit; no spinning

    // ================= finalizer (last arriver) =================
    const uint32_t nbuf = min(ld_rlx32(gCnt), BUFCAP);

    // level 2: bits[20:10] count+sum hists from buf
    for (int i = tid; i < 2048; i += 256) { sh[0][i] = 0; ssum[i] = 0ull; }
    __syncthreads();
    for (uint32_t i = (uint32_t)tid; i < nbuf; i += 256) {
        const uint32_t b = ld_rlx32(&buf[i]);
        const uint32_t b2 = (b >> 10) & 0x7FFu;
        atomicAdd(&sh[0][b2], 1u);
        atomicAdd(&ssum[b2], (unsigned long long)fixv(__uint_as_float(b)));
    }
    __syncthreads();
    selstep<8, false>(sh[0], needed0, wtot, res, tid);
    const uint32_t s1      = res[0];
    const uint32_t needed1 = res[1];
    {
        uint64_t sb = 0;
#pragma unroll
        for (int k = 0; k < 8; ++k) {
            const uint32_t b = (uint32_t)tid * 8u + (uint32_t)k;
            if (b > s1) sb += ssum[b];
        }
#pragma unroll
        for (int off = 32; off > 0; off >>= 1)
            sb += __shfl_down((unsigned long long)sb, off, 64);
        if (lane == 0) usum[wv] = sb;
        __syncthreads();
        if (tid == 0) sAcc2 = usum[0] + usum[1] + usum[2] + usum[3];
    }
    __syncthreads();

    // level 3: bits[9:0] within (s0,s1)
    for (int i = tid; i < 1024; i += 256) { sh[0][i] = 0; ssum[i] = 0ull; }
    __syncthreads();
    for (uint32_t i = (uint32_t)tid; i < nbuf; i += 256) {
        const uint32_t b = ld_rlx32(&buf[i]);
        if (((b >> 10) & 0x7FFu) == s1) {
            const uint32_t b3 = b & 0x3FFu;
            atomicAdd(&sh[0][b3], 1u);
            atomicAdd(&ssum[b3], (unsigned long long)fixv(__uint_as_float(b)));
        }
    }
    __syncthreads();
    selstep<4, false>(sh[0], needed1, wtot, res, tid);
    const uint32_t s2      = res[0];
    const uint32_t needed2 = res[1];
    const uint32_t T = (s0 << 21) | (s1 << 10) | s2;
    {
        uint64_t sb = 0;
#pragma unroll
        for (int k = 0; k < 4; ++k) {
            const uint32_t b = (uint32_t)tid * 4u + (uint32_t)k;
            if (b > s2) sb += ssum[b];
        }
#pragma unroll
        for (int off = 32; off > 0; off >>= 1)
            sb += __shfl_down((unsigned long long)sb, off, 64);
        if (lane == 0) usum[wv] = sb;
        __syncthreads();
        if (tid == 0) {
            const uint64_t total =
                usum[0] + usum[1] + usum[2] + usum[3] + sAcc2 + ld_rlx64(gSum);
            const double tval = (double)__uint_as_float(T);
            const double loss = ((double)total * (1.0 / FIX_SCALE) +
                                 (double)needed2 * tval) / (double)TOPK;
            out[0] = (float)loss;
        }
    }
}

extern "C" void kernel_launch(void* const* d_in, const int* in_sizes, int n_in,
                              void* d_out, int out_size, void* d_ws, size_t ws_size,
                              hipStream_t stream) {
    const float* x   = (const float*)d_in[0];
    const int*   lab = (const int*)d_in[1];
    float*       out = (float*)d_out;
    uint32_t*    gws = (uint32_t*)d_ws;

    hipMemsetAsync(gws, 0, WS_ZERO_BYTES, stream);

    void* args[] = {(void*)&x, (void*)&lab, (void*)&gws, (void*)&out};
    hipLaunchCooperativeKernel((const void*)triplet_kernel, dim3(B), dim3(256),
                               args, 0, stream);
}